// Round 4
// baseline (513.532 us; speedup 1.0000x reference)
//
#include <hip/hip_runtime.h>

#define BT 16
#define NN 8192
#define FIN 128
#define FOUT 32
#define NB 512       // BT*FOUT
#define SPLITK 4
#define KSPAN (NN / SPLITK)   // 2048
#define BKK 64
#define NSTAGE (KSPAN / BKK)  // 32

typedef __attribute__((ext_vector_type(8))) short short8;
typedef __attribute__((ext_vector_type(4))) float float4v;

__device__ __forceinline__ float bf2f(unsigned short u) {
    unsigned v = ((unsigned)u) << 16;
    float f;
    __builtin_memcpy(&f, &v, 4);
    return f;
}
__device__ __forceinline__ unsigned short f2bf(float f) {
    unsigned u;
    __builtin_memcpy(&u, &f, 4);
    u += 0x7FFFu + ((u >> 16) & 1u);   // RNE
    return (unsigned short)(u >> 16);
}

// async global->LDS, 16 B per lane; LDS dest = wave-uniform base + lane*16
__device__ __forceinline__ void load_lds16(const unsigned short* g, unsigned short* l) {
    __builtin_amdgcn_global_load_lds((const __attribute__((address_space(1))) void*)g,
                                     (__attribute__((address_space(3))) void*)l, 16, 0, 0);
}

// ---------------------------------------------------------------------------
// Sniff bf16-vs-fp32 (proven R1-R3) + zero sumh[512].
// ---------------------------------------------------------------------------
__global__ void sniff_dtype(const unsigned* __restrict__ Wraw, unsigned* __restrict__ flag,
                            float* __restrict__ sumh) {
    int lane = threadIdx.x;
    unsigned u = Wraw[lane];
    float f = bf2f((unsigned short)(u & 0xFFFFu));
    float af = fabsf(f);
    bool plaus = (af > 1e-5f) && (af < 1e3f);
    unsigned long long msk = __ballot(plaus);
    if (lane == 0) flag[0] = (__popcll(msk) >= 32) ? 1u : 0u;
#pragma unroll
    for (int r = 0; r < 8; ++r) sumh[lane + 64 * r] = 0.f;
}

// ---------------------------------------------------------------------------
// K01 fused: [0,128) zero s2 | [128,1152) pack adj->P2 | [1152,2176) h=inp@W
// P2 layout: uint2 per (word-pair, i): P2v[(kw>>1)*NN + i] = {word kw, word kw+1}
// so K2 fetches both BKK=64 k-words of a row with one coalesced dwordx2.
// ---------------------------------------------------------------------------
__launch_bounds__(256)
__global__ void k01(const int* __restrict__ adj, uint2* __restrict__ P2v,
                    const void* __restrict__ inp_raw, const void* __restrict__ W_raw,
                    unsigned short* __restrict__ Ht, float* __restrict__ sumh,
                    float4* __restrict__ s2v, const unsigned* __restrict__ flagp) {
    __shared__ __align__(16) unsigned short Wt[32 * 136];
    int bid = blockIdx.x;
    const int tid = threadIdx.x;

    if (bid < 128) {                 // ---- zero s2 (131072 floats = 32768 float4)
        float4 z; z.x = z.y = z.z = z.w = 0.f;
        s2v[bid * 256 + tid] = z;
        return;
    }
    bid -= 128;
    if (bid < 1024) {                // ---- pack: bit b of word kw = adj[kw*32+b][i] > 0
        const int i = (bid & 31) * 256 + tid;
        const int k0 = (bid >> 5) * 256;
        unsigned words[8];
#pragma unroll
        for (int wk = 0; wk < 8; ++wk) {
            unsigned wv = 0;
            const int* gp = adj + (size_t)(k0 + wk * 32) * NN + i;
#pragma unroll
            for (int kk = 0; kk < 32; ++kk)
                wv |= (gp[(size_t)kk * NN] > 0 ? 1u : 0u) << kk;
            words[wk] = wv;
        }
        const int w2base = k0 >> 6;
#pragma unroll
        for (int p = 0; p < 4; ++p) {
            uint2 t; t.x = words[2 * p]; t.y = words[2 * p + 1];
            P2v[(size_t)(w2base + p) * NN + i] = t;
        }
        return;
    }
    bid -= 1024;                     // ---- h-part (R2/R3 body, proven)
    const int bt = bid >> 6;
    const int j0 = (bid & 63) * 128;
    const bool isbf = (*flagp != 0u);

    if (isbf) {
        const unsigned short* Wb = (const unsigned short*)W_raw;
#pragma unroll
        for (int r = 0; r < 16; ++r) {
            int idx = tid + 256 * r, i = idx >> 5, o = idx & 31;
            Wt[o * 136 + i] = Wb[idx];
        }
    } else {
        const float* Wf = (const float*)W_raw;
#pragma unroll
        for (int r = 0; r < 16; ++r) {
            int idx = tid + 256 * r, i = idx >> 5, o = idx & 31;
            Wt[o * 136 + i] = f2bf(Wf[idx]);
        }
    }
    __syncthreads();

    const int lane = tid & 63, w = tid >> 6;
    const int m = lane & 15, q = lane >> 4;
    const int mt = (w & 1) * 16;
    const int nt = (w >> 1) * 64;

    float4v acc[4];
#pragma unroll
    for (int c = 0; c < 4; ++c) { float4v z = {0.f, 0.f, 0.f, 0.f}; acc[c] = z; }

#pragma unroll
    for (int kstep = 0; kstep < 4; ++kstep) {
        short8 af = *(const short8*)&Wt[(mt + m) * 136 + kstep * 32 + q * 8];
#pragma unroll
        for (int c = 0; c < 4; ++c) {
            int j = j0 + nt + c * 16 + m;
            short8 bfrag;
            if (isbf) {
                bfrag = *(const short8*)((const unsigned short*)inp_raw +
                        ((size_t)bt * NN + j) * FIN + kstep * 32 + q * 8);
            } else {
                const float* fp = (const float*)inp_raw + ((size_t)bt * NN + j) * FIN + kstep * 32 + q * 8;
                float4 f0 = *(const float4*)fp;
                float4 f1 = *(const float4*)(fp + 4);
                union { unsigned short u[8]; short8 v; } t;
                t.u[0] = f2bf(f0.x); t.u[1] = f2bf(f0.y); t.u[2] = f2bf(f0.z); t.u[3] = f2bf(f0.w);
                t.u[4] = f2bf(f1.x); t.u[5] = f2bf(f1.y); t.u[6] = f2bf(f1.z); t.u[7] = f2bf(f1.w);
                bfrag = t.v;
            }
            acc[c] = __builtin_amdgcn_mfma_f32_16x16x32_bf16(af, bfrag, acc[c], 0, 0, 0);
        }
    }

#pragma unroll
    for (int c = 0; c < 4; ++c) {
#pragma unroll
        for (int e = 0; e < 4; ++e) {
            int o = mt + q * 4 + e;
            int j = j0 + nt + c * 16 + m;
            Ht[(size_t)(bt * FOUT + o) * NN + j] = f2bf(acc[c][e]);
        }
    }
#pragma unroll
    for (int e = 0; e < 4; ++e) {
        float s = acc[0][e] + acc[1][e] + acc[2][e] + acc[3][e];
        s += __shfl_xor(s, 1); s += __shfl_xor(s, 2);
        s += __shfl_xor(s, 4); s += __shfl_xor(s, 8);
        if (m == 0) atomicAdd(&sumh[bt * FOUT + mt + q * 4 + e], s);
    }
}

// ---------------------------------------------------------------------------
// K2: tile 256(i) x 128(n) x BK=64, split-K=4, 256 thr = 4 waves.
// Wave w owns rows [w*64, w*64+64) x all 128 cols: acc 4x8.
// A-fragments expanded bitmask->VGPR (no As LDS, no duplicate expansion);
// B staged via global_load_lds x16 + XOR swizzle (proven R3); LDS = Bs only.
// Epilogue folds a2-dot + m-lane reduce + atomic into s2.
// ---------------------------------------------------------------------------
__launch_bounds__(256, 2)
__global__ void k2_gemm(const uint2* __restrict__ P2v, const unsigned short* __restrict__ Ht,
                        const void* __restrict__ a_raw, float* __restrict__ s2,
                        const unsigned* __restrict__ flagp) {
    __shared__ __align__(16) unsigned short Bs[128 * 64];    // 16 KB
    const int tid = threadIdx.x;
    const int n0 = blockIdx.x * 128;
    const int i0 = blockIdx.y * 256;
    const int z = blockIdx.z;
    const int lane = tid & 63, w = tid >> 6;
    const int m = lane & 15, q = lane >> 4;
    const int wm = w * 64;              // wave's row base (distinct per wave)
    const int qs8 = q * 8;
    const bool isbf = (*flagp != 0u);

    // DMA source offsets (4 calls x 16 B/lane): unit u -> LDS slot (n=u>>3, kb=u&7),
    // source k-block kb ^ (n&7).
    int boff[4];
#pragma unroll
    for (int c = 0; c < 4; ++c) {
        int u = c * 256 + tid;
        int n = u >> 3;
        int kbs = (u & 7) ^ (n & 7);
        boff[c] = (n0 + n) * NN + kbs * 8;
    }

    // A bit-word pointer: row = wm + r*16 + m, stage s adds s*NN
    const uint2* Pp = P2v + (size_t)(z * (KSPAN >> 6)) * NN + i0 + wm + m;

    float4v acc[4][8];
#pragma unroll
    for (int r = 0; r < 4; ++r)
#pragma unroll
        for (int c = 0; c < 8; ++c) { float4v zz = {0.f, 0.f, 0.f, 0.f}; acc[r][c] = zz; }

    for (int s = 0; s < NSTAGE; ++s) {
        const int k0 = z * KSPAN + s * BKK;
        __syncthreads();
#pragma unroll
        for (int c = 0; c < 4; ++c)
            load_lds16(Ht + boff[c] + k0, &Bs[(c * 256 + w * 64) * 8]);
        uint2 wr[4];
#pragma unroll
        for (int r = 0; r < 4; ++r)
            wr[r] = Pp[(size_t)s * NN + r * 16];
        __syncthreads();   // vmcnt(0) drains DMA + word loads

#pragma unroll
        for (int ks = 0; ks < 2; ++ks) {
            short8 af[4];
#pragma unroll
            for (int r = 0; r < 4; ++r) {
                unsigned wd = ks ? wr[r].y : wr[r].x;
                union { unsigned u[4]; short8 v; } t;
#pragma unroll
                for (int j2 = 0; j2 < 4; ++j2) {
                    unsigned b0 = (wd >> (qs8 + 2 * j2)) & 1u;
                    unsigned b1 = (wd >> (qs8 + 2 * j2 + 1)) & 1u;
                    t.u[j2] = b0 * 0x3F80u + b1 * 0x3F800000u;
                }
                af[r] = t.v;
            }
#pragma unroll
            for (int c = 0; c < 8; ++c) {
                int row = c * 16 + m;
                int kbs = (ks * 4 + q) ^ (m & 7);
                short8 bfr = *(const short8*)&Bs[row * 64 + kbs * 8];
#pragma unroll
                for (int r = 0; r < 4; ++r)
                    acc[r][c] = __builtin_amdgcn_mfma_f32_16x16x32_bf16(af[r], bfr, acc[r][c], 0, 0, 0);
            }
        }
    }

    // ---- fused epilogue: per (r,e): gi fixed; 4 bt-groups (cols 32g..32g+31)
    const int btbase = n0 >> 5;
#pragma unroll
    for (int r = 0; r < 4; ++r) {
#pragma unroll
        for (int e = 0; e < 4; ++e) {
            int gi = i0 + wm + r * 16 + q * 4 + e;
            float a2m, a2m16;
            if (isbf) {
                const unsigned short* ab = (const unsigned short*)a_raw;
                a2m   = bf2f(ab[(size_t)(FOUT + m) * NN + gi]);
                a2m16 = bf2f(ab[(size_t)(FOUT + 16 + m) * NN + gi]);
            } else {
                const float* afp = (const float*)a_raw;
                a2m   = afp[(size_t)(FOUT + m) * NN + gi];
                a2m16 = afp[(size_t)(FOUT + 16 + m) * NN + gi];
            }
#pragma unroll
            for (int g = 0; g < 4; ++g) {
                float sv = acc[r][2 * g][e] * a2m + acc[r][2 * g + 1][e] * a2m16;
                sv += __shfl_xor(sv, 1); sv += __shfl_xor(sv, 2);
                sv += __shfl_xor(sv, 4); sv += __shfl_xor(sv, 8);
                if (m == 0) atomicAdd(&s2[(size_t)(btbase + g) * NN + gi], sv);
            }
        }
    }
}

// ---------------------------------------------------------------------------
// K3: s = s2 + sum_o h*a1 ; out = relu(s * sumh[bt,:])
// ---------------------------------------------------------------------------
__launch_bounds__(256)
__global__ void k3_out(const unsigned short* __restrict__ Ht, const float* __restrict__ s2,
                       const float* __restrict__ sumh, const void* __restrict__ a_raw,
                       void* __restrict__ out_raw, const unsigned* __restrict__ flagp) {
    const int i = blockIdx.x * 256 + threadIdx.x;
    const int bt = blockIdx.y;
    const bool isbf = (*flagp != 0u);

    float s = s2[(size_t)bt * NN + i];
    if (isbf) {
        const unsigned short* ab = (const unsigned short*)a_raw;
#pragma unroll
        for (int o = 0; o < 32; ++o) {
            float h = bf2f(Ht[(size_t)(bt * FOUT + o) * NN + i]);
            s += h * bf2f(ab[(size_t)o * NN + i]);
        }
    } else {
        const float* afp = (const float*)a_raw;
#pragma unroll
        for (int o = 0; o < 32; ++o) {
            float h = bf2f(Ht[(size_t)(bt * FOUT + o) * NN + i]);
            s += h * afp[(size_t)o * NN + i];
        }
    }

    float ov[32];
#pragma unroll
    for (int o = 0; o < 32; ++o) ov[o] = fmaxf(s * sumh[bt * FOUT + o], 0.f);

    size_t ob = ((size_t)bt * NN + i) * FOUT;
    if (isbf) {
        unsigned short* o16 = (unsigned short*)out_raw + ob;
#pragma unroll
        for (int c = 0; c < 8; ++c) {
            ushort4 p;
            p.x = f2bf(ov[c * 4 + 0]); p.y = f2bf(ov[c * 4 + 1]);
            p.z = f2bf(ov[c * 4 + 2]); p.w = f2bf(ov[c * 4 + 3]);
            *(ushort4*)(o16 + c * 4) = p;
        }
    } else {
        float* of = (float*)out_raw + ob;
#pragma unroll
        for (int c = 0; c < 8; ++c) {
            float4 v;
            v.x = ov[c * 4 + 0]; v.y = ov[c * 4 + 1]; v.z = ov[c * 4 + 2]; v.w = ov[c * 4 + 3];
            *(float4*)(of + c * 4) = v;
        }
    }
}

// ---------------------------------------------------------------------------
extern "C" void kernel_launch(void* const* d_in, const int* in_sizes, int n_in,
                              void* d_out, int out_size, void* d_ws, size_t ws_size,
                              hipStream_t stream) {
    const void* inp = d_in[0];
    const int* adj = (const int*)d_in[1];
    const void* W = d_in[2];
    const void* a = d_in[3];

    char* ws = (char*)d_ws;
    unsigned short* Ht = (unsigned short*)ws;                    // 8 MB
    uint2* P2v = (uint2*)(ws + 8388608);                         // 8 MB
    unsigned* flag = (unsigned*)(ws + 16777216);                 // 4 B
    float* s2 = (float*)(ws + 16781312);                         // 512 KB
    float* sumh = (float*)(ws + 16781312 + 524288);              // 2 KB

    sniff_dtype<<<1, 64, 0, stream>>>((const unsigned*)W, flag, sumh);
    k01<<<2176, 256, 0, stream>>>(adj, P2v, inp, W, Ht, sumh, (float4*)s2, flag);
    k2_gemm<<<dim3(NB / 128, NN / 256, SPLITK), 256, 0, stream>>>(P2v, Ht, a, s2, flag);
    k3_out<<<dim3(NN / 256, BT), 256, 0, stream>>>(Ht, s2, sumh, a, d_out, flag);
}